// Round 5
// baseline (667.963 us; speedup 1.0000x reference)
//
#include <hip/hip_runtime.h>
#include <hip/hip_bf16.h>
#include <math.h>

#define NB 4
#define LL 16384
#define CC 256
#define NHD 8
#define DH 32
#define MROWS (NB*LL)   // 65536

typedef __hip_bfloat16 bf16;
typedef __attribute__((ext_vector_type(8))) short short8;
typedef __attribute__((ext_vector_type(4))) float floatx4;

__device__ __forceinline__ float u2f(unsigned short u) {
  return __uint_as_float(((unsigned)u) << 16);
}
__device__ __forceinline__ unsigned short f2u(float f) {
  bf16 t = __float2bfloat16(f);
  unsigned short u;
  __builtin_memcpy(&u, &t, 2);
  return u;
}

// ---------------- f32 -> bf16 bulk convert (8 elems/thread) --------------
__global__ __launch_bounds__(256) void convert_kernel(
    const float* __restrict__ in, bf16* __restrict__ out, int n8)
{
  int i = blockIdx.x*256 + threadIdx.x;
  if (i >= n8) return;
  const float4* p = (const float4*)in + (size_t)i*2;
  float4 f0 = p[0], f1 = p[1];
  unsigned short t[8] = {f2u(f0.x),f2u(f0.y),f2u(f0.z),f2u(f0.w),
                         f2u(f1.x),f2u(f1.y),f2u(f1.z),f2u(f1.w)};
  *(uint4*)(out + (size_t)i*8) = *(uint4*)t;
}

// ---------------- MFMA GEMM with async A staging -------------------------
// C[M,N] = act( A[M,K] @ B[N,K]^T )
// A: bf16, split at K0 (A0 ld=K0 for k<K0, A1 ld=K-K0 for k>=K0)
// B: f32 weights [N,K] (L2-resident, sync-converted at staging)
// Tiles 128x128, BK=32, 4 waves of 64x64 (4x4 of 16x16x32).
template<bool RELU>
__global__ __launch_bounds__(256) void gemm_as(
    const bf16* __restrict__ A0, int K0, const bf16* __restrict__ A1,
    const float* __restrict__ B, bf16* __restrict__ C,
    int M, int N, int K)
{
  __shared__ __align__(16) unsigned short As[128*32];  // 8 KB, unpadded (global_load_lds)
  __shared__ __align__(16) unsigned short Bs[128*32];  // 8 KB
  const int tid  = threadIdx.x;
  const int lane = tid & 63, wave = tid >> 6;
  const int wm = wave & 1, wn = wave >> 1;
  const int bm = blockIdx.y, bn = blockIdx.x;
  const int l15 = lane & 15, quad = lane >> 4;

  floatx4 acc[4][4] = {};

  for (int kt = 0; kt < K; kt += 32) {
    // ---- async stage A tile (128 x 32 bf16): 8 chunks of 1024B, 2/wave ----
    {
      const bf16* aSrc = (kt < K0) ? A0 : A1;
      const int lda    = (kt < K0) ? K0 : (K - K0);
      const int kcol   = ((kt < K0) ? kt : (kt - K0)) + ((lane & 3) << 3);
      #pragma unroll
      for (int i = 0; i < 2; i++) {
        int c = wave*2 + i;
        int r = c*16 + (lane >> 2);
        const bf16* g = aSrc + (size_t)(bm*128 + r)*lda + kcol;
        __builtin_amdgcn_global_load_lds(
            (const __attribute__((address_space(1))) void*)g,
            (__attribute__((address_space(3))) void*)(As + c*512),
            16, 0, 0);
      }
    }
    // ---- sync stage B tile (128 x 32 bf16 from f32 weights) ----
    {
      int row = tid >> 1, kc = (tid & 1) << 4;
      const float* p = B + (size_t)(bn*128 + row)*K + kt + kc;
      float4 f0 = ((const float4*)p)[0];
      float4 f1 = ((const float4*)p)[1];
      float4 f2 = ((const float4*)p)[2];
      float4 f3 = ((const float4*)p)[3];
      unsigned short t[16] = {
        f2u(f0.x),f2u(f0.y),f2u(f0.z),f2u(f0.w),
        f2u(f1.x),f2u(f1.y),f2u(f1.z),f2u(f1.w),
        f2u(f2.x),f2u(f2.y),f2u(f2.z),f2u(f2.w),
        f2u(f3.x),f2u(f3.y),f2u(f3.z),f2u(f3.w)};
      *(uint4*)&Bs[row*32 + kc]     = *(uint4*)t;
      *(uint4*)&Bs[row*32 + kc + 8] = *(uint4*)(t+8);
    }
    __syncthreads();
    // ---- fragments + MFMA ----
    short8 a[4], b[4];
    #pragma unroll
    for (int i = 0; i < 4; i++) {
      a[i] = *(const short8*)&As[(wm*64 + i*16 + l15)*32 + quad*8];
      b[i] = *(const short8*)&Bs[(wn*64 + i*16 + l15)*32 + quad*8];
    }
    #pragma unroll
    for (int i = 0; i < 4; i++)
      #pragma unroll
      for (int j = 0; j < 4; j++)
        acc[i][j] = __builtin_amdgcn_mfma_f32_16x16x32_bf16(a[i], b[j], acc[i][j], 0, 0, 0);
    __syncthreads();
  }

  // ---- epilogue: C/D layout col=lane&15, row=quad*4+reg ----
  const int row0 = bm*128 + wm*64 + quad*4;
  const int col0 = bn*128 + wn*64 + l15;
  #pragma unroll
  for (int i = 0; i < 4; i++) {
    #pragma unroll
    for (int j = 0; j < 4; j++) {
      #pragma unroll
      for (int r = 0; r < 4; r++) {
        float v = acc[i][j][r];
        if (RELU) v = fmaxf(v, 0.f);
        C[(size_t)(row0 + i*16 + r)*N + (col0 + j*16)] = __float2bfloat16(v);
      }
    }
  }
}

// ---------------- elu+1 then interleaved RoPE, in-place (one buffer) -----
__global__ __launch_bounds__(256) void rope_elu_kernel(bf16* __restrict__ q)
{
  int idx = blockIdx.x*256 + threadIdx.x;   // one (row, pair); 128 pairs/row
  int row = idx >> 7;
  int p   = idx & 127;          // global pair in row
  int pp  = p & 15;             // pair in head
  int t   = pp >> 1;            // frequency index 0..7
  int l   = row & (LL-1);
  int gi  = l >> 7;             // grid row (W=128)
  int gj  = l & 127;            // grid col
  float pos = (pp & 1) ? (float)(gj+1) : (float)(gi+1);
  float dv  = expf(-1.15129254650564f * (float)t);  // ln(10000)/8
  float ang = pos * dv;
  float s = sinf(ang), c = cosf(ang);
  size_t base = ((size_t)row << 8) + (p << 1);
  ushort2 uq = *(const ushort2*)(q + base);
  float x0 = u2f(uq.x), x1 = u2f(uq.y);
  x0 = x0 > 0.f ? x0 + 1.f : expf(x0);
  x1 = x1 > 0.f ? x1 + 1.f : expf(x1);
  ushort2 oq; oq.x = f2u(fmaf(x0, c, -x1*s)); oq.y = f2u(fmaf(x1, c, x0*s));
  *(ushort2*)(q + base) = oq;
}

__global__ __launch_bounds__(256) void zero_kernel(float* __restrict__ p, int n)
{
  int i = blockIdx.x*256 + threadIdx.x;
  if (i < n) p[i] = 0.f;
}

// ---------------- KV[n,h,d,e] = sum_s K[n,s,h,d]*V[n,s,h,e]; Ksum too -----
__global__ __launch_bounds__(256) void kv_kernel(
    const bf16* __restrict__ Kr, const bf16* __restrict__ V,
    float* __restrict__ KV, float* __restrict__ Ksum)
{
  __shared__ __align__(16) float Ks[64][32];
  __shared__ __align__(16) float Vs[64][32];
  const int nh = blockIdx.x;               // n*8+h
  const int n = nh >> 3, h = nh & 7;
  const int s0 = blockIdx.y * 1024;        // 16 chunks of 1024
  const int tid = threadIdx.x;
  const int d = tid >> 3, e0 = (tid & 7) << 2;
  float acc[4] = {0.f,0.f,0.f,0.f};
  float ksl = 0.f;
  for (int sub = 0; sub < 1024; sub += 64) {
    #pragma unroll
    for (int i = 0; i < 4; i++) {
      int flat = (tid + i*256) << 1;        // pair index *2 = element
      int sl = flat >> 5, dd = flat & 31;
      size_t g = (((size_t)(n*LL + s0 + sub + sl) * NHD + h) << 5) + dd;
      ushort2 uk = *(const ushort2*)(Kr + g);
      ushort2 uv = *(const ushort2*)(V + g);
      Ks[sl][dd]   = u2f(uk.x); Ks[sl][dd+1] = u2f(uk.y);
      Vs[sl][dd]   = u2f(uv.x); Vs[sl][dd+1] = u2f(uv.y);
    }
    __syncthreads();
    #pragma unroll 8
    for (int ss = 0; ss < 64; ss++) {
      float kd = Ks[ss][d];
      float4 v4 = *(const float4*)&Vs[ss][e0];
      acc[0] = fmaf(kd, v4.x, acc[0]);
      acc[1] = fmaf(kd, v4.y, acc[1]);
      acc[2] = fmaf(kd, v4.z, acc[2]);
      acc[3] = fmaf(kd, v4.w, acc[3]);
    }
    if (tid < 32) {
      #pragma unroll 8
      for (int ss = 0; ss < 64; ss++) ksl += Ks[ss][tid];
    }
    __syncthreads();
  }
  float* kvp = KV + ((size_t)nh << 10) + (d << 5) + e0;
  atomicAdd(kvp+0, acc[0]); atomicAdd(kvp+1, acc[1]);
  atomicAdd(kvp+2, acc[2]); atomicAdd(kvp+3, acc[3]);
  if (tid < 32) atomicAdd(Ksum + (nh << 5) + tid, ksl);
}

// ---------------- out[l,h,e] = (Q_h . KV_h[:,e]) / (Q_h . Ksum_h + eps) ---
__global__ __launch_bounds__(256) void attn_out_kernel(
    const bf16* __restrict__ Qr, const float* __restrict__ KV,
    const float* __restrict__ Ksum, bf16* __restrict__ Out)
{
  __shared__ float KVs[8192];
  __shared__ float Kss[256];
  __shared__ float Qs[16][256];
  const int blk = blockIdx.x;            // 4096 blocks, 16 rows each
  const int n = blk >> 10;               // 1024 blocks per batch
  const int tid = threadIdx.x;
  const size_t rowBase = (size_t)blk * 16;
  for (int i = tid; i < 8192; i += 256) KVs[i] = KV[((size_t)n << 13) + i];
  Kss[tid] = Ksum[(n << 8) + tid];
  for (int i = tid; i < 4096; i += 256) ((float*)Qs)[i] = u2f(*(const unsigned short*)(Qr + (rowBase << 8) + i));
  __syncthreads();
  const int h = tid >> 5, e = tid & 31;
  const float* kvh = &KVs[(h << 10) + e];
  const float* ksh = &Kss[h << 5];
  for (int r = 0; r < 16; r++) {
    const float* qh = &Qs[r][h << 5];
    float denom = 1e-6f;
    float num = 0.f;
    #pragma unroll
    for (int d = 0; d < 32; d++) {
      float qd = qh[d];
      denom = fmaf(qd, ksh[d], denom);
      num   = fmaf(qd, kvh[d << 5], num);
    }
    Out[((rowBase + r) << 8) + tid] = __float2bfloat16(num / denom);
  }
}

// ---------------- LayerNorm over 256, bf16 ws in/out, f32 params ---------
__global__ __launch_bounds__(256) void ln_kernel(
    const bf16* __restrict__ X, const float* __restrict__ g, const float* __restrict__ b,
    bf16* __restrict__ Out)
{
  __shared__ float ps[4], psq[4], stat[2];
  int row = blockIdx.x, tid = threadIdx.x;
  float v = __bfloat162float(X[((size_t)row << 8) + tid]);
  float s = v, sq = v*v;
  #pragma unroll
  for (int o = 32; o > 0; o >>= 1) {
    s  += __shfl_down(s, o, 64);
    sq += __shfl_down(sq, o, 64);
  }
  if ((tid & 63) == 0) { ps[tid>>6] = s; psq[tid>>6] = sq; }
  __syncthreads();
  if (tid == 0) {
    float S = ps[0]+ps[1]+ps[2]+ps[3];
    float SQ = psq[0]+psq[1]+psq[2]+psq[3];
    float mean = S * (1.f/256.f);
    float var = SQ * (1.f/256.f) - mean*mean;
    stat[0] = mean; stat[1] = rsqrtf(var + 1e-5f);
  }
  __syncthreads();
  float mean = stat[0], rstd = stat[1];
  Out[((size_t)row << 8) + tid] = __float2bfloat16(
      (v - mean)*rstd*g[tid] + b[tid]);
}

// ---------------- final: out = x + LN(h2), f32 x/out ---------------------
__global__ __launch_bounds__(256) void ln_add_kernel(
    const bf16* __restrict__ X, const float* __restrict__ g, const float* __restrict__ b,
    const float* __restrict__ xin, float* __restrict__ Out)
{
  __shared__ float ps[4], psq[4], stat[2];
  int row = blockIdx.x, tid = threadIdx.x;
  size_t idx = ((size_t)row << 8) + tid;
  float v = __bfloat162float(X[idx]);
  float s = v, sq = v*v;
  #pragma unroll
  for (int o = 32; o > 0; o >>= 1) {
    s  += __shfl_down(s, o, 64);
    sq += __shfl_down(sq, o, 64);
  }
  if ((tid & 63) == 0) { ps[tid>>6] = s; psq[tid>>6] = sq; }
  __syncthreads();
  if (tid == 0) {
    float S = ps[0]+ps[1]+ps[2]+ps[3];
    float SQ = psq[0]+psq[1]+psq[2]+psq[3];
    float mean = S * (1.f/256.f);
    float var = SQ * (1.f/256.f) - mean*mean;
    stat[0] = mean; stat[1] = rsqrtf(var + 1e-5f);
  }
  __syncthreads();
  float mean = stat[0], rstd = stat[1];
  float lnv = (v - mean)*rstd*g[tid] + b[tid];
  Out[idx] = xin[idx] + lnv;
}

extern "C" void kernel_launch(void* const* d_in, const int* in_sizes, int n_in,
                              void* d_out, int out_size, void* d_ws, size_t ws_size,
                              hipStream_t stream) {
  const float* x   = (const float*)d_in[0];
  const float* src = (const float*)d_in[1];
  const float* Wq  = (const float*)d_in[2];
  const float* Wk  = (const float*)d_in[3];
  const float* Wv  = (const float*)d_in[4];
  const float* Wm  = (const float*)d_in[5];
  const float* W1  = (const float*)d_in[6];
  const float* W2  = (const float*)d_in[7];
  const float* g1  = (const float*)d_in[8];
  const float* b1  = (const float*)d_in[9];
  const float* g2  = (const float*)d_in[10];
  const float* b2  = (const float*)d_in[11];
  float* out = (float*)d_out;

  // 4 regions x 32 MB = 128 MB total workspace (known-safe range).
  bf16* ws = (bf16*)d_ws;
  const size_t BUFH = (size_t)MROWS * CC;   // 16,777,216 bf16 = 32 MB
  bf16* R0 = ws;               // xb (x in bf16) -- live whole pipeline
  bf16* R1 = ws + BUFH;        // sb -> KV(front)+ -> msg -> h2
  bf16* R2 = ws + 2*BUFH;      // k -> q -> h1(lo)
  bf16* R3 = ws + 3*BUFH;      // v -> attn -> h1(hi)
  float* KV   = (float*)R1;                 // 32768 f32 (in dead sb window)
  float* Ksum = KV + NB*NHD*DH*DH;          // 1024 f32

  dim3 blk(256);
  const int n8 = MROWS*CC/8;
  // bf16 conversions of x and src
  convert_kernel<<<(n8+255)/256, blk, 0, stream>>>(x,   R0, n8);
  convert_kernel<<<(n8+255)/256, blk, 0, stream>>>(src, R1, n8);
  // k/v projections from sb(R1)
  gemm_as<false><<<dim3(CC/128, MROWS/128), blk, 0, stream>>>(R1, CC, nullptr, Wk, R2, MROWS, CC, CC);
  gemm_as<false><<<dim3(CC/128, MROWS/128), blk, 0, stream>>>(R1, CC, nullptr, Wv, R3, MROWS, CC, CC);
  // rope(k); then KV/Ksum (sb dead -> KV lives at R1 base)
  rope_elu_kernel<<<(MROWS*128)/256, blk, 0, stream>>>(R2);
  int kvN = NB*NHD*DH*DH + NB*NHD*DH;
  zero_kernel<<<(kvN+255)/256, blk, 0, stream>>>(KV, kvN);
  kv_kernel<<<dim3(NB*NHD, 16), blk, 0, stream>>>(R2, R3, KV, Ksum);
  // q projection from xb(R0) into R2 (k dead), rope(q)
  gemm_as<false><<<dim3(CC/128, MROWS/128), blk, 0, stream>>>(R0, CC, nullptr, Wq, R2, MROWS, CC, CC);
  rope_elu_kernel<<<(MROWS*128)/256, blk, 0, stream>>>(R2);
  // attention apply: q(R2) -> attn(R3) (v dead)
  attn_out_kernel<<<MROWS/16, blk, 0, stream>>>(R2, KV, Ksum, R3);
  // msg = LN1(attn @ Wm^T): attn(R3) -> msg(R1) (KV dead after attn)
  gemm_as<false><<<dim3(CC/128, MROWS/128), blk, 0, stream>>>(R3, CC, nullptr, Wm, R1, MROWS, CC, CC);
  ln_kernel<<<MROWS, blk, 0, stream>>>(R1, g1, b1, R1);
  // h1 = relu([xb(R0) | msg(R1)] @ W1^T) -> R2..R3 (64 MB contiguous)
  gemm_as<true><<<dim3(2*CC/128, MROWS/128), blk, 0, stream>>>(R0, CC, R1, W1, R2, MROWS, 2*CC, 2*CC);
  // h2 = h1(R2) @ W2^T -> R1 (msg dead)
  gemm_as<false><<<dim3(CC/128, MROWS/128), blk, 0, stream>>>(R2, 2*CC, nullptr, W2, R1, MROWS, CC, 2*CC);
  // out = x + LN2(h2)
  ln_add_kernel<<<MROWS, blk, 0, stream>>>(R1, g2, b2, x, out);
}

// Round 6
// 572.771 us; speedup vs baseline: 1.1662x; 1.1662x over previous
//
#include <hip/hip_runtime.h>
#include <hip/hip_bf16.h>
#include <math.h>

#define NB 4
#define LL 16384
#define CC 256
#define NHD 8
#define DH 32
#define MROWS (NB*LL)   // 65536

typedef __hip_bfloat16 bf16;
typedef __attribute__((ext_vector_type(8))) short short8;
typedef __attribute__((ext_vector_type(4))) float floatx4;

__device__ __forceinline__ float u2f(unsigned short u) {
  return __uint_as_float(((unsigned)u) << 16);
}
__device__ __forceinline__ unsigned short f2u(float f) {
  bf16 t = __float2bfloat16(f);
  unsigned short u;
  __builtin_memcpy(&u, &t, 2);
  return u;
}

// ---------------- f32 -> bf16 bulk convert (8 elems/thread) --------------
__global__ __launch_bounds__(256) void convert_kernel(
    const float* __restrict__ in, bf16* __restrict__ out, int n8)
{
  int i = blockIdx.x*256 + threadIdx.x;
  if (i >= n8) return;
  const float4* p = (const float4*)in + (size_t)i*2;
  float4 f0 = p[0], f1 = p[1];
  unsigned short t[8] = {f2u(f0.x),f2u(f0.y),f2u(f0.z),f2u(f0.w),
                         f2u(f1.x),f2u(f1.y),f2u(f1.z),f2u(f1.w)};
  *(uint4*)(out + (size_t)i*8) = *(uint4*)t;
}

// ---------------- all weights f32 -> bf16, one dispatch ------------------
// dst layout (elements): Wq 0 | Wk 65536 | Wv 131072 | Wm 196608 | W1 262144 | W2 524288
__global__ __launch_bounds__(256) void convert_weights_kernel(
    const float* __restrict__ Wq, const float* __restrict__ Wk,
    const float* __restrict__ Wv, const float* __restrict__ Wm,
    const float* __restrict__ W1, const float* __restrict__ W2,
    bf16* __restrict__ dst)
{
  int i = blockIdx.x*256 + threadIdx.x;    // 8-elem unit; total 81920 units
  const float* src; int off8;
  if      (i < 8192)  { src = Wq; off8 = i; }
  else if (i < 16384) { src = Wk; off8 = i-8192; }
  else if (i < 24576) { src = Wv; off8 = i-16384; }
  else if (i < 32768) { src = Wm; off8 = i-24576; }
  else if (i < 65536) { src = W1; off8 = i-32768; }
  else                { src = W2; off8 = i-65536; }
  const float4* p = (const float4*)src + (size_t)off8*2;
  float4 f0 = p[0], f1 = p[1];
  unsigned short t[8] = {f2u(f0.x),f2u(f0.y),f2u(f0.z),f2u(f0.w),
                         f2u(f1.x),f2u(f1.y),f2u(f1.z),f2u(f1.w)};
  *(uint4*)(dst + (size_t)i*8) = *(uint4*)t;
}

// ---------------- m97-style MFMA GEMM, fully async staging ---------------
// C[M,N] = epi( A[M,K] @ B[N,K]^T ), all bf16.
// A split at K0 (A0 ld=K0 for k<K0, A1 ld=K-K0 beyond) for the concat case.
// EPI: 0 none, 1 relu, 2 elu+1 then interleaved RoPE.
// 128x128 tile, BK=32, 4 waves (2x2 of 64x64), XCD-aware 1-D block swizzle.
template<int EPI>
__global__ __launch_bounds__(256) void gemm_m97(
    const bf16* __restrict__ A0, int K0, const bf16* __restrict__ A1,
    const bf16* __restrict__ B, bf16* __restrict__ C,
    int M, int N, int K)
{
  __shared__ __align__(16) unsigned short As[128*32];  // 8 KB
  __shared__ __align__(16) unsigned short Bs[128*32];  // 8 KB
  const int tid  = threadIdx.x;
  const int lane = tid & 63, wave = tid >> 6;
  const int wm = wave & 1, wn = wave >> 1;
  const int l15 = lane & 15, quad = lane >> 4;

  // swizzle: blocks with same bm, all bn sit 8 apart -> same XCD L2 shares A
  const int nbn = N >> 7;                       // 2 or 4
  const int sh  = (nbn == 2) ? 4 : 5;           // log2(8*nbn)
  const int w   = blockIdx.x & ((1 << sh) - 1);
  const int g   = blockIdx.x >> sh;
  const int bm  = g*8 + (w & 7);
  const int bn  = w >> 3;

  const int srow  = tid >> 2;          // 0..63
  const int skcol = (tid & 3) << 3;    // 0,8,16,24 (elements)

  floatx4 acc[4][4] = {};

  for (int kt = 0; kt < K; kt += 32) {
    const bf16* aSrc; int lda, kof;
    if (kt < K0) { aSrc = A0; lda = K0;     kof = kt; }
    else         { aSrc = A1; lda = K - K0; kof = kt - K0; }
    #pragma unroll
    for (int c = 0; c < 2; c++) {     // A tile rows 0..63 / 64..127
      const bf16* gp = aSrc + (size_t)(bm*128 + c*64 + srow)*lda + kof + skcol;
      __builtin_amdgcn_global_load_lds(
          (const __attribute__((address_space(1))) void*)gp,
          (__attribute__((address_space(3))) void*)(As + c*2048 + tid*8),
          16, 0, 0);
    }
    #pragma unroll
    for (int c = 0; c < 2; c++) {     // B tile
      const bf16* gp = B + (size_t)(bn*128 + c*64 + srow)*K + kt + skcol;
      __builtin_amdgcn_global_load_lds(
          (const __attribute__((address_space(1))) void*)gp,
          (__attribute__((address_space(3))) void*)(Bs + c*2048 + tid*8),
          16, 0, 0);
    }
    __syncthreads();
    short8 a[4], b[4];
    #pragma unroll
    for (int i = 0; i < 4; i++) {
      a[i] = *(const short8*)&As[(wm*64 + i*16 + l15)*32 + quad*8];
      b[i] = *(const short8*)&Bs[(wn*64 + i*16 + l15)*32 + quad*8];
    }
    #pragma unroll
    for (int i = 0; i < 4; i++)
      #pragma unroll
      for (int j = 0; j < 4; j++)
        acc[i][j] = __builtin_amdgcn_mfma_f32_16x16x32_bf16(a[i], b[j], acc[i][j], 0, 0, 0);
    __syncthreads();
  }

  // epilogue: C/D layout col=lane&15, row=quad*4+reg
  const int row0 = bm*128 + wm*64 + quad*4;
  const int col0 = bn*128 + wn*64 + l15;
  if (EPI == 2) {
    // pair-channel constants, fixed per lane (col0&31 == l15)
    const int pp_e = l15 >> 1;        // j even
    const int pp_o = pp_e + 8;        // j odd
    const int par  = pp_e & 1;        // i-angle (0) vs j-angle (1)
    const float dv_e = __expf(-1.15129254650564f * (float)(pp_e >> 1));
    const float dv_o = __expf(-1.15129254650564f * (float)(pp_o >> 1));
    const float sgn = (l15 & 1) ? 1.f : -1.f;
    #pragma unroll
    for (int i = 0; i < 4; i++) {
      #pragma unroll
      for (int r = 0; r < 4; r++) {
        int row = row0 + i*16 + r;
        int l = row & (LL-1);
        float pos = par ? (float)((l & 127) + 1) : (float)((l >> 7) + 1);
        float ae = pos * dv_e, ao = pos * dv_o;
        float se = __sinf(ae), ce = __cosf(ae);
        float so = __sinf(ao), co = __cosf(ao);
        #pragma unroll
        for (int j = 0; j < 4; j++) {
          float s = (j & 1) ? so : se;
          float c = (j & 1) ? co : ce;
          float v = acc[i][j][r];
          v = v > 0.f ? v + 1.f : __expf(v);   // elu+1
          float p = __shfl_xor(v, 1, 64);      // pair partner channel
          float o = fmaf(v, c, sgn * p * s);
          C[(size_t)row*N + (col0 + j*16)] = __float2bfloat16(o);
        }
      }
    }
  } else {
    #pragma unroll
    for (int i = 0; i < 4; i++)
      #pragma unroll
      for (int j = 0; j < 4; j++)
        #pragma unroll
        for (int r = 0; r < 4; r++) {
          float v = acc[i][j][r];
          if (EPI == 1) v = fmaxf(v, 0.f);
          C[(size_t)(row0 + i*16 + r)*N + (col0 + j*16)] = __float2bfloat16(v);
        }
  }
}

__global__ __launch_bounds__(256) void zero_kernel(float* __restrict__ p, int n)
{
  int i = blockIdx.x*256 + threadIdx.x;
  if (i < n) p[i] = 0.f;
}

// ---------------- KV[n,h,d,e] = sum_s K[n,s,h,d]*V[n,s,h,e]; Ksum too -----
__global__ __launch_bounds__(256) void kv_kernel(
    const bf16* __restrict__ Kr, const bf16* __restrict__ V,
    float* __restrict__ KV, float* __restrict__ Ksum)
{
  __shared__ __align__(16) float Ks[64][32];
  __shared__ __align__(16) float Vs[64][32];
  const int nh = blockIdx.x;               // n*8+h
  const int n = nh >> 3, h = nh & 7;
  const int s0 = blockIdx.y * 1024;        // 16 chunks of 1024
  const int tid = threadIdx.x;
  const int d = tid >> 3, e0 = (tid & 7) << 2;
  float acc[4] = {0.f,0.f,0.f,0.f};
  float ksl = 0.f;
  for (int sub = 0; sub < 1024; sub += 64) {
    #pragma unroll
    for (int i = 0; i < 4; i++) {
      int flat = (tid + i*256) << 1;        // pair index *2 = element
      int sl = flat >> 5, dd = flat & 31;
      size_t g = (((size_t)(n*LL + s0 + sub + sl) * NHD + h) << 5) + dd;
      ushort2 uk = *(const ushort2*)(Kr + g);
      ushort2 uv = *(const ushort2*)(V + g);
      Ks[sl][dd]   = u2f(uk.x); Ks[sl][dd+1] = u2f(uk.y);
      Vs[sl][dd]   = u2f(uv.x); Vs[sl][dd+1] = u2f(uv.y);
    }
    __syncthreads();
    #pragma unroll 8
    for (int ss = 0; ss < 64; ss++) {
      float kd = Ks[ss][d];
      float4 v4 = *(const float4*)&Vs[ss][e0];
      acc[0] = fmaf(kd, v4.x, acc[0]);
      acc[1] = fmaf(kd, v4.y, acc[1]);
      acc[2] = fmaf(kd, v4.z, acc[2]);
      acc[3] = fmaf(kd, v4.w, acc[3]);
    }
    if (tid < 32) {
      #pragma unroll 8
      for (int ss = 0; ss < 64; ss++) ksl += Ks[ss][tid];
    }
    __syncthreads();
  }
  float* kvp = KV + ((size_t)nh << 10) + (d << 5) + e0;
  atomicAdd(kvp+0, acc[0]); atomicAdd(kvp+1, acc[1]);
  atomicAdd(kvp+2, acc[2]); atomicAdd(kvp+3, acc[3]);
  if (tid < 32) atomicAdd(Ksum + (nh << 5) + tid, ksl);
}

// ---------------- out[l,h,e] = (Q_h . KV_h[:,e]) / (Q_h . Ksum_h + eps) ---
__global__ __launch_bounds__(256) void attn_out_kernel(
    const bf16* __restrict__ Qr, const float* __restrict__ KV,
    const float* __restrict__ Ksum, bf16* __restrict__ Out)
{
  __shared__ float KVs[8192];
  __shared__ float Kss[256];
  __shared__ float Qs[16][256];
  const int blk = blockIdx.x;            // 4096 blocks, 16 rows each
  const int n = blk >> 10;               // 1024 blocks per batch
  const int tid = threadIdx.x;
  const size_t rowBase = (size_t)blk * 16;
  for (int i = tid; i < 8192; i += 256) KVs[i] = KV[((size_t)n << 13) + i];
  Kss[tid] = Ksum[(n << 8) + tid];
  for (int i = tid; i < 4096; i += 256) ((float*)Qs)[i] = u2f(*(const unsigned short*)(Qr + (rowBase << 8) + i));
  __syncthreads();
  const int h = tid >> 5, e = tid & 31;
  const float* kvh = &KVs[(h << 10) + e];
  const float* ksh = &Kss[h << 5];
  for (int r = 0; r < 16; r++) {
    const float* qh = &Qs[r][h << 5];
    float denom = 1e-6f;
    float num = 0.f;
    #pragma unroll
    for (int d = 0; d < 32; d++) {
      float qd = qh[d];
      denom = fmaf(qd, ksh[d], denom);
      num   = fmaf(qd, kvh[d << 5], num);
    }
    Out[((rowBase + r) << 8) + tid] = __float2bfloat16(num / denom);
  }
}

// ---------------- LayerNorm over 256, bf16 ws in/out, f32 params ---------
__global__ __launch_bounds__(256) void ln_kernel(
    const bf16* __restrict__ X, const float* __restrict__ g, const float* __restrict__ b,
    bf16* __restrict__ Out)
{
  __shared__ float ps[4], psq[4], stat[2];
  int row = blockIdx.x, tid = threadIdx.x;
  float v = __bfloat162float(X[((size_t)row << 8) + tid]);
  float s = v, sq = v*v;
  #pragma unroll
  for (int o = 32; o > 0; o >>= 1) {
    s  += __shfl_down(s, o, 64);
    sq += __shfl_down(sq, o, 64);
  }
  if ((tid & 63) == 0) { ps[tid>>6] = s; psq[tid>>6] = sq; }
  __syncthreads();
  if (tid == 0) {
    float S = ps[0]+ps[1]+ps[2]+ps[3];
    float SQ = psq[0]+psq[1]+psq[2]+psq[3];
    float mean = S * (1.f/256.f);
    float var = SQ * (1.f/256.f) - mean*mean;
    stat[0] = mean; stat[1] = rsqrtf(var + 1e-5f);
  }
  __syncthreads();
  float mean = stat[0], rstd = stat[1];
  Out[((size_t)row << 8) + tid] = __float2bfloat16(
      (v - mean)*rstd*g[tid] + b[tid]);
}

// ---------------- final: out = x + LN(h2), f32 x/out ---------------------
__global__ __launch_bounds__(256) void ln_add_kernel(
    const bf16* __restrict__ X, const float* __restrict__ g, const float* __restrict__ b,
    const float* __restrict__ xin, float* __restrict__ Out)
{
  __shared__ float ps[4], psq[4], stat[2];
  int row = blockIdx.x, tid = threadIdx.x;
  size_t idx = ((size_t)row << 8) + tid;
  float v = __bfloat162float(X[idx]);
  float s = v, sq = v*v;
  #pragma unroll
  for (int o = 32; o > 0; o >>= 1) {
    s  += __shfl_down(s, o, 64);
    sq += __shfl_down(sq, o, 64);
  }
  if ((tid & 63) == 0) { ps[tid>>6] = s; psq[tid>>6] = sq; }
  __syncthreads();
  if (tid == 0) {
    float S = ps[0]+ps[1]+ps[2]+ps[3];
    float SQ = psq[0]+psq[1]+psq[2]+psq[3];
    float mean = S * (1.f/256.f);
    float var = SQ * (1.f/256.f) - mean*mean;
    stat[0] = mean; stat[1] = rsqrtf(var + 1e-5f);
  }
  __syncthreads();
  float mean = stat[0], rstd = stat[1];
  float lnv = (v - mean)*rstd*g[tid] + b[tid];
  Out[idx] = xin[idx] + lnv;
}

extern "C" void kernel_launch(void* const* d_in, const int* in_sizes, int n_in,
                              void* d_out, int out_size, void* d_ws, size_t ws_size,
                              hipStream_t stream) {
  const float* x   = (const float*)d_in[0];
  const float* src = (const float*)d_in[1];
  const float* Wq  = (const float*)d_in[2];
  const float* Wk  = (const float*)d_in[3];
  const float* Wv  = (const float*)d_in[4];
  const float* Wm  = (const float*)d_in[5];
  const float* W1  = (const float*)d_in[6];
  const float* W2  = (const float*)d_in[7];
  const float* g1  = (const float*)d_in[8];
  const float* b1  = (const float*)d_in[9];
  const float* g2  = (const float*)d_in[10];
  const float* b2  = (const float*)d_in[11];
  float* out = (float*)d_out;

  bf16* ws = (bf16*)d_ws;
  const size_t BUFH = (size_t)MROWS * CC;   // 16,777,216 bf16 = 32 MB
  bf16* R0 = ws;               // xb (live until W1 gemm)
  bf16* R1 = ws + BUFH;        // sb -> q -> h1(lo)
  bf16* R2 = ws + 2*BUFH;      // k -> attn -> h1(hi)
  bf16* R3 = ws + 3*BUFH;      // v -> msg -> h2
  bf16* WB = ws + 4*BUFH;      // bf16 weights, 655360 elems (1.25 MB)
  bf16* wq = WB, *wk = WB+65536, *wv = WB+131072, *wm = WB+196608,
      *w1 = WB+262144, *w2 = WB+524288;
  float* KV   = (float*)(WB + 655360);      // 32768 f32
  float* Ksum = KV + NB*NHD*DH*DH;          // 1024 f32
  // total ws: 128 MB + 1.25 MB + 132 KB

  dim3 blk(256);
  const int n8 = MROWS*CC/8;
  convert_kernel<<<(n8+255)/256, blk, 0, stream>>>(x,   R0, n8);
  convert_kernel<<<(n8+255)/256, blk, 0, stream>>>(src, R1, n8);
  convert_weights_kernel<<<320, blk, 0, stream>>>(Wq, Wk, Wv, Wm, W1, W2, WB);

  const int G256 = (MROWS/128)*(CC/128);    // 1024 blocks
  const int G512 = (MROWS/128)*(2*CC/128);  // 2048 blocks
  // k = rope(elu(sb@Wk^T)+1) -> R2 ; v = sb@Wv^T -> R3
  gemm_m97<2><<<G256, blk, 0, stream>>>(R1, CC, nullptr, wk, R2, MROWS, CC, CC);
  gemm_m97<0><<<G256, blk, 0, stream>>>(R1, CC, nullptr, wv, R3, MROWS, CC, CC);
  // KV + Ksum
  int kvN = NB*NHD*DH*DH + NB*NHD*DH;
  zero_kernel<<<(kvN+255)/256, blk, 0, stream>>>(KV, kvN);
  kv_kernel<<<dim3(NB*NHD, 16), blk, 0, stream>>>(R2, R3, KV, Ksum);
  // q = rope(elu(xb@Wq^T)+1) -> R1 (sb dead)
  gemm_m97<2><<<G256, blk, 0, stream>>>(R0, CC, nullptr, wq, R1, MROWS, CC, CC);
  // attn: q(R1) -> R2 (k dead)
  attn_out_kernel<<<MROWS/16, blk, 0, stream>>>(R1, KV, Ksum, R2);
  // msg = LN1(attn @ Wm^T): attn(R2) -> R3 (v dead)
  gemm_m97<0><<<G256, blk, 0, stream>>>(R2, CC, nullptr, wm, R3, MROWS, CC, CC);
  ln_kernel<<<MROWS, blk, 0, stream>>>(R3, g1, b1, R3);
  // h1 = relu([xb(R0) | msg(R3)] @ W1^T) -> R1..R2 (64 MB contiguous)
  gemm_m97<1><<<G512, blk, 0, stream>>>(R0, CC, R3, w1, R1, MROWS, 2*CC, 2*CC);
  // h2 = h1(R1,K=512) @ W2^T -> R3 (msg dead)
  gemm_m97<0><<<G256, blk, 0, stream>>>(nullptr, 0, R1, w2, R3, MROWS, CC, 2*CC);
  // out = x + LN2(h2)
  ln_add_kernel<<<MROWS, blk, 0, stream>>>(R3, g2, b2, x, out);
}